// Round 7
// baseline (122.926 us; speedup 1.0000x reference)
//
#include <hip/hip_runtime.h>

#define IMG_W 2048
#define NUM_NODES 255
#define NLEAF 128
#define DEPTH 7
#define RS 68                       // padded LDS row stride (floats); 16B-chunk group = (row+q)%8
#define NBLK 256                    // fusedK grid

// DPP xor-butterfly add over 16-lane groups (VALU pipe, not LDS).
// Masks {1,2,7,8}: xor1,xor2 give quad sums; xor7 adds the partner quad of the
// 8-group; xor8 the partner 8-group. All 16 lanes end bit-identical.
template<int CTRL>
__device__ __forceinline__ float dpp_add(float x) {
    int v = __builtin_amdgcn_update_dpp(0, __float_as_int(x), CTRL, 0xF, 0xF, true);
    return x + __int_as_float(v);
}
__device__ __forceinline__ float group16_sum(float x) {
    x = dpp_add<0xB1>(x);   // quad_perm [1,0,3,2]  : xor 1
    x = dpp_add<0x4E>(x);   // quad_perm [2,3,0,1]  : xor 2
    x = dpp_add<0x141>(x);  // row_half_mirror      : xor 7
    x = dpp_add<0x128>(x);  // row_ror:8            : xor 8
    return x;
}

// ---------------- K1: descend + block-local accumulate, NO global atomics ----
__global__ __launch_bounds__(1024, 4) void fusedK(const float* __restrict__ img,
                                                  const float* __restrict__ nodes,
                                                  float* __restrict__ leaf_out,
                                                  float* __restrict__ S_partial,
                                                  unsigned* __restrict__ cnt_partial)
{
    __shared__ float nds[NUM_NODES * RS];   // 69360 B; first 128*RS floats reused as Sl
    __shared__ unsigned cntl[NLEAF];
    float* Sl = nds;                        // overlay (phase 2)

    const int t = threadIdx.x;
    const int b = blockIdx.x;
    const int g = t >> 4;          // patch-group 0..63
    const int q = t & 15;          // quad within patch (elements 4q..4q+3)
    const int q4 = q * 4;

    if (t < NLEAF) cntl[t] = 0u;

    // fill node table (padded rows)
    const float4* ng = (const float4*)nodes;
    for (int i = t; i < NUM_NODES * 16; i += 1024) {
        *(float4*)&nds[(i >> 4) * RS + (i & 15) * 4] = ng[i];
    }

    // prefetch 4 chunks' patch quads (element e=4q+j -> pixel (q>>1, (q&1)*4+j))
    float4 xv[4];
    #pragma unroll
    for (int ch = 0; ch < 4; ++ch) {
        const int p = b * 256 + ch * 64 + g;
        const int r = p >> 8, c = p & 255;
        xv[ch] = *(const float4*)(img + (size_t)(r * 8 + (q >> 1)) * IMG_W + c * 8 + (q & 1) * 4);
    }
    __syncthreads();

    // phase 1: descent (nodes from LDS; bank-group (row+q)%8 balanced by construction)
    int leaf[4];
    #pragma unroll
    for (int ch = 0; ch < 4; ++ch) {
        const float4 x = xv[ch];
        int cur = 0;
        #pragma unroll
        for (int lvl = 0; lvl < DEPTH; ++lvl) {
            const int c0 = 2 * cur + 1;
            const float* base = &nds[c0 * RS + q4];
            const float4 a  = *(const float4*)(base);        // child c0, quad q
            const float4 bb = *(const float4*)(base + RS);   // child c0+1, quad q
            float s0 = 0.f, s1 = 0.f, d;
            d = a.x  - x.x; s0 = fmaf(d, d, s0);
            d = a.y  - x.y; s0 = fmaf(d, d, s0);
            d = a.z  - x.z; s0 = fmaf(d, d, s0);
            d = a.w  - x.w; s0 = fmaf(d, d, s0);
            d = bb.x - x.x; s1 = fmaf(d, d, s1);
            d = bb.y - x.y; s1 = fmaf(d, d, s1);
            d = bb.z - x.z; s1 = fmaf(d, d, s1);
            d = bb.w - x.w; s1 = fmaf(d, d, s1);
            s0 = group16_sum(s0);
            s1 = group16_sum(s1);
            cur = (s1 < s0) ? (c0 + 1) : c0;   // ref: d1 < d0 picks c1 (strict)
        }
        leaf[ch] = cur;
        if (q == 0) leaf_out[b * 256 + ch * 64 + g] = (float)cur;
    }
    __syncthreads();                        // all descents done reading nds

    // phase 2: overlay -> zero per-leaf accumulators
    for (int i = t; i < NLEAF * RS; i += 1024) Sl[i] = 0.0f;
    __syncthreads();

    #pragma unroll
    for (int ch = 0; ch < 4; ++ch) {
        const int L = leaf[ch] - 127;
        const float4 x = xv[ch];
        float* dst = &Sl[L * RS + q4];      // group (L+q)%8: balanced for random L
        atomicAdd(dst + 0, x.x);
        atomicAdd(dst + 1, x.y);
        atomicAdd(dst + 2, x.z);
        atomicAdd(dst + 3, x.w);
        if (q == 0) atomicAdd(&cntl[L], 1u);
    }
    __syncthreads();

    // write compact block partials with plain coalesced float4 stores
    float4* Sp = (float4*)(S_partial + (size_t)b * (NLEAF * 64));
    for (int i = t; i < NLEAF * 16; i += 1024) {
        const int row = i >> 4, qq = i & 15;
        Sp[i] = *(const float4*)&Sl[row * RS + qq * 4];
    }
    if (t < NLEAF) cnt_partial[b * NLEAF + t] = cntl[t];
}

// ---------------- K2: deterministic partial reduction ------------------------
__global__ __launch_bounds__(256) void reduceK(const float* __restrict__ S_partial,
                                               const unsigned* __restrict__ cnt_partial,
                                               float* __restrict__ S,
                                               unsigned* __restrict__ cnt)
{
    const int e = blockIdx.x * 256 + threadIdx.x;   // 8192 elements
    float a0 = 0.f, a1 = 0.f, a2 = 0.f, a3 = 0.f, a4 = 0.f, a5 = 0.f, a6 = 0.f, a7 = 0.f;
    for (int b = 0; b < NBLK; b += 8) {             // coalesced across lanes, 8-way ILP
        a0 += S_partial[(size_t)(b + 0) * 8192 + e];
        a1 += S_partial[(size_t)(b + 1) * 8192 + e];
        a2 += S_partial[(size_t)(b + 2) * 8192 + e];
        a3 += S_partial[(size_t)(b + 3) * 8192 + e];
        a4 += S_partial[(size_t)(b + 4) * 8192 + e];
        a5 += S_partial[(size_t)(b + 5) * 8192 + e];
        a6 += S_partial[(size_t)(b + 6) * 8192 + e];
        a7 += S_partial[(size_t)(b + 7) * 8192 + e];
    }
    S[e] = ((a0 + a1) + (a2 + a3)) + ((a4 + a5) + (a6 + a7));
    if (e < NLEAF) {
        unsigned c = 0;
        for (int b = 0; b < NBLK; ++b) c += cnt_partial[b * NLEAF + e];
        cnt[e] = c;
    }
}

// ---------------- K3: node update (254x64x128 contraction) -------------------
__global__ __launch_bounds__(256) void updateK(const float* __restrict__ nodes,
                                               const float* __restrict__ S,
                                               const unsigned* __restrict__ cnt,
                                               float* __restrict__ out)
{
    const int gid = blockIdx.x * 256 + threadIdx.x;
    if (gid >= NUM_NODES * 64) return;
    const int n = gid >> 6, k = gid & 63;
    const float nd = nodes[gid];
    if (n == 0) { out[gid] = nd; return; }

    const int pos = n + 1;                 // 1-based heap index
    const int Ln = 31 - __clz(pos);        // node level, 1..7
    float su = 0.f, sc = 0.f;
    #pragma unroll 8
    for (int L = 0; L < NLEAF; ++L) {
        const int a = (128 + L) >> (7 - Ln);   // leaf's ancestor at level Ln
        const int x = pos ^ a;
        const int state = (x == 0) ? Ln : (Ln - (31 - __clz(x)) - 1);
        const float lr = 0.3f * ((float)(1 << state) * (1.0f / 128.0f));
        su = fmaf(lr, S[L * 64 + k], su);
        sc = fmaf(lr, (float)cnt[L], sc);
    }
    const float invP = 1.0f / 65536.0f;
    out[gid] = nd + su * invP - (sc * invP) * nd;
}

extern "C" void kernel_launch(void* const* d_in, const int* in_sizes, int n_in,
                              void* d_out, int out_size, void* d_ws, size_t ws_size,
                              hipStream_t stream)
{
    const float* img   = (const float*)d_in[0];   // 2048*2048 f32
    const float* nodes = (const float*)d_in[1];   // 255*64 f32

    float* out_nodes = (float*)d_out;                 // 255*64
    float* out_leaf  = out_nodes + NUM_NODES * 64;    // 65536 (leaf index as f32)

    float*    S_partial   = (float*)d_ws;                            // 256*8192 f32 = 8 MB
    unsigned* cnt_partial = (unsigned*)(S_partial + NBLK * 8192);    // 256*128 u32
    float*    S           = (float*)(cnt_partial + NBLK * NLEAF);    // 8192 f32
    unsigned* cnt         = (unsigned*)(S + 8192);                   // 128 u32

    fusedK<<<NBLK, 1024, 0, stream>>>(img, nodes, out_leaf, S_partial, cnt_partial);
    reduceK<<<32, 256, 0, stream>>>(S_partial, cnt_partial, S, cnt);
    updateK<<<64, 256, 0, stream>>>(nodes, S, cnt, out_nodes);
}

// Round 8
// 118.788 us; speedup vs baseline: 1.0348x; 1.0348x over previous
//
#include <hip/hip_runtime.h>

#define IMG_W 2048
#define NUM_NODES 255
#define NLEAF 128
#define DEPTH 7
#define RS 68                       // padded LDS row stride (floats); 16B-chunk group = (row+q)%8

// DPP xor-butterfly add over 16-lane groups (VALU pipe, not LDS).
// Masks {1,2,7,8}: xor1,xor2 give quad sums; xor7 adds the partner quad of the
// 8-group; xor8 the partner 8-group. All 16 lanes end bit-identical.
template<int CTRL>
__device__ __forceinline__ float dpp_add(float x) {
    int v = __builtin_amdgcn_update_dpp(0, __float_as_int(x), CTRL, 0xF, 0xF, true);
    return x + __int_as_float(v);
}
__device__ __forceinline__ float group16_sum(float x) {
    x = dpp_add<0xB1>(x);   // quad_perm [1,0,3,2]  : xor 1
    x = dpp_add<0x4E>(x);   // quad_perm [2,3,0,1]  : xor 2
    x = dpp_add<0x141>(x);  // row_half_mirror      : xor 7
    x = dpp_add<0x128>(x);  // row_ror:8            : xor 8
    return x;
}

// ---------------- K1: descent only, 16 lanes/patch, nodes in LDS -------------
// 512-thread blocks, 69.4 KB LDS -> 2 blocks/CU (16 waves/CU, 4/SIMD).
__global__ __launch_bounds__(512, 4) void descendK(const float* __restrict__ img,
                                                   const float* __restrict__ nodes,
                                                   float* __restrict__ leaf_out)
{
    __shared__ float nds[NUM_NODES * RS];   // 69360 B

    const int t = threadIdx.x;
    const int b = blockIdx.x;
    const int g = t >> 4;          // patch-group 0..31
    const int q = t & 15;          // quad within patch (elements 4q..4q+3)
    const int q4 = q * 4;

    // fill node table (padded rows)
    const float4* ng = (const float4*)nodes;
    for (int i = t; i < NUM_NODES * 16; i += 512) {
        *(float4*)&nds[(i >> 4) * RS + (i & 15) * 4] = ng[i];
    }

    // prefetch both chunks' patch quads (element e=4q+j -> pixel (q>>1, (q&1)*4+j))
    float4 xv[2];
    #pragma unroll
    for (int ch = 0; ch < 2; ++ch) {
        const int p = b * 64 + ch * 32 + g;
        const int r = p >> 8, c = p & 255;
        xv[ch] = *(const float4*)(img + (size_t)(r * 8 + (q >> 1)) * IMG_W + c * 8 + (q & 1) * 4);
    }
    __syncthreads();

    #pragma unroll
    for (int ch = 0; ch < 2; ++ch) {
        const float4 x = xv[ch];
        int cur = 0;
        #pragma unroll
        for (int lvl = 0; lvl < DEPTH; ++lvl) {
            const int c0 = 2 * cur + 1;
            const float* base = &nds[c0 * RS + q4];
            const float4 a  = *(const float4*)(base);        // child c0, quad q
            const float4 bb = *(const float4*)(base + RS);   // child c0+1, quad q
            float s0 = 0.f, s1 = 0.f, d;
            d = a.x  - x.x; s0 = fmaf(d, d, s0);
            d = a.y  - x.y; s0 = fmaf(d, d, s0);
            d = a.z  - x.z; s0 = fmaf(d, d, s0);
            d = a.w  - x.w; s0 = fmaf(d, d, s0);
            d = bb.x - x.x; s1 = fmaf(d, d, s1);
            d = bb.y - x.y; s1 = fmaf(d, d, s1);
            d = bb.z - x.z; s1 = fmaf(d, d, s1);
            d = bb.w - x.w; s1 = fmaf(d, d, s1);
            s0 = group16_sum(s0);
            s1 = group16_sum(s1);
            cur = (s1 < s0) ? (c0 + 1) : c0;   // ref: d1 < d0 picks c1 (strict)
        }
        if (q == 0) leaf_out[b * 64 + ch * 32 + g] = (float)cur;
    }
}

// ---------------- K2: per-leaf accumulation (sweep; no same-address in-instr) -
__global__ __launch_bounds__(256) void accumK(const float* __restrict__ img,
                                              const float* __restrict__ leaf_out,
                                              float* __restrict__ S,
                                              unsigned* __restrict__ cnt)
{
    __shared__ float XN[256 * RS];     // staged patches (69632 B)
    __shared__ float Sl[NLEAF * RS];   // per-leaf accumulators (34816 B)
    __shared__ int   Ll[256];
    __shared__ unsigned cntl[NLEAF];

    const int t = threadIdx.x;
    const int b = blockIdx.x;
    const int p = b * 256 + t;
    const int r = p >> 8, c = p & 255;

    for (int i = t; i < NLEAF * RS; i += 256) Sl[i] = 0.0f;
    if (t < NLEAF) cntl[t] = 0u;

    // stage my patch into row t (16B-aligned b128 writes)
    {
        float* st = &XN[t * RS];
        #pragma unroll
        for (int ki = 0; ki < 8; ++ki) {
            const float4* rowp = (const float4*)(img + (size_t)(r * 8 + ki) * IMG_W + c * 8);
            *(float4*)&st[ki * 8]     = rowp[0];
            *(float4*)&st[ki * 8 + 4] = rowp[1];
        }
    }
    Ll[t] = (int)leaf_out[p] - 127;
    __syncthreads();

    // wave w sweeps its 64 patches; lane k = element k. Same row L, distinct k:
    // zero same-address serialization; banks (4pl+k)%32 -> 2 lanes/bank (free).
    const int w = t >> 6, k = t & 63;
    for (int i = 0; i < 64; ++i) {
        const int pl = w * 64 + i;
        const int L  = Ll[pl];                 // wave-uniform broadcast
        atomicAdd(&Sl[L * RS + k], XN[pl * RS + k]);
        if (k == 0) atomicAdd(&cntl[L], 1u);
    }
    __syncthreads();

    // flush block sums to global S (skip zeros; lane-distinct addresses)
    for (int i = t; i < NLEAF * 64; i += 256) {
        const float v = Sl[(i >> 6) * RS + (i & 63)];
        if (v != 0.0f) atomicAdd(&S[i], v);
    }
    if (t < NLEAF && cntl[t] != 0u) atomicAdd(&cnt[t], cntl[t]);
}

// ---------------- K3: node update (254x64x128 contraction) -------------------
__global__ __launch_bounds__(256) void updateK(const float* __restrict__ nodes,
                                               const float* __restrict__ S,
                                               const unsigned* __restrict__ cnt,
                                               float* __restrict__ out)
{
    const int gid = blockIdx.x * 256 + threadIdx.x;
    if (gid >= NUM_NODES * 64) return;
    const int n = gid >> 6, k = gid & 63;
    const float nd = nodes[gid];
    if (n == 0) { out[gid] = nd; return; }

    const int pos = n + 1;                 // 1-based heap index
    const int Ln = 31 - __clz(pos);        // node level, 1..7
    float su = 0.f, sc = 0.f;
    #pragma unroll 8
    for (int L = 0; L < NLEAF; ++L) {
        const int a = (128 + L) >> (7 - Ln);   // leaf's ancestor at level Ln
        const int x = pos ^ a;
        const int state = (x == 0) ? Ln : (Ln - (31 - __clz(x)) - 1);
        const float lr = 0.3f * ((float)(1 << state) * (1.0f / 128.0f));
        su = fmaf(lr, S[L * 64 + k], su);
        sc = fmaf(lr, (float)cnt[L], sc);
    }
    const float invP = 1.0f / 65536.0f;
    out[gid] = nd + su * invP - (sc * invP) * nd;
}

extern "C" void kernel_launch(void* const* d_in, const int* in_sizes, int n_in,
                              void* d_out, int out_size, void* d_ws, size_t ws_size,
                              hipStream_t stream)
{
    const float* img   = (const float*)d_in[0];   // 2048*2048 f32
    const float* nodes = (const float*)d_in[1];   // 255*64 f32

    float* out_nodes = (float*)d_out;                 // 255*64
    float* out_leaf  = out_nodes + NUM_NODES * 64;    // 65536 (leaf index as f32)

    float*    S   = (float*)d_ws;                     // 128*64 f32
    unsigned* cnt = (unsigned*)(S + NLEAF * 64);      // 128 u32

    hipMemsetAsync(d_ws, 0, (NLEAF * 64) * sizeof(float) + NLEAF * sizeof(unsigned), stream);
    descendK<<<1024, 512, 0, stream>>>(img, nodes, out_leaf);
    accumK<<<256, 256, 0, stream>>>(img, out_leaf, S, cnt);
    updateK<<<64, 256, 0, stream>>>(nodes, S, cnt, out_nodes);
}